// Round 4
// baseline (956.574 us; speedup 1.0000x reference)
//
#include <hip/hip_runtime.h>

#define B_ 256
#define T_ 2048
#define H_ 64

typedef float f32x2 __attribute__((ext_vector_type(2)));
typedef float f32x4 __attribute__((ext_vector_type(4)));

__device__ __forceinline__ void pk_fma(f32x2& d, f32x2 a, f32x2 b) {
    asm("v_pk_fma_f32 %0, %1, %2, %0" : "+v"(d) : "v"(a), "v"(b));
}
__device__ __forceinline__ f32x2 pk_add(f32x2 a, f32x2 b) {
    f32x2 d;
    asm("v_pk_add_f32 %0, %1, %2" : "=v"(d) : "v"(a), "v"(b));
    return d;
}

__device__ __forceinline__ float fast_sigmoid(float v) {
    float e = __builtin_amdgcn_exp2f(-1.4426950408889634f * v);
    return __builtin_amdgcn_rcpf(1.0f + e);
}

__device__ __forceinline__ float fast_tanh(float v) {
    float e = __builtin_amdgcn_exp2f(2.8853900817779268f * v);
    return fmaf(-2.0f, __builtin_amdgcn_rcpf(1.0f + e), 1.0f);
}

__device__ __forceinline__ float readlane_f(float v, int idx) {
    return __builtin_bit_cast(float,
        __builtin_amdgcn_readlane(__builtin_bit_cast(int, v), idx));
}

// One wave per batch row; lane j owns hidden channel j, computes all 3 gate
// rows. KEY FIX vs R3: weights are laundered through asm volatile after the
// preload, so their defs are non-rematerializable and the 192 weight floats
// must stay live in VGPRs across the whole time loop (amdgpu_waves_per_eu(1,1)
// gives regalloc the full 512-VGPR budget -> no scratch spill). h lives in a
// 64-float LDS buffer: 1 ds_write + 16 broadcast ds_read_b128 per step, zero
// barriers, zero bank conflicts (uniform address).
__global__ __launch_bounds__(64, 1) __attribute__((amdgpu_waves_per_eu(1, 1)))
void gru_kernel(const float* __restrict__ x,
                const float* __restrict__ W_ih,
                const float* __restrict__ W_hh,
                const float* __restrict__ b_ih,
                const float* __restrict__ b_hh,
                float* __restrict__ out)
{
    __shared__ float shh[H_];

    const int lane = threadIdx.x;
    const int b    = blockIdx.x;

    // ---- preload W_hh rows {lane, 64+lane, 128+lane} ----
    f32x2 wr[32], wz[32], wn[32];
    {
        const f32x4* pr = (const f32x4*)(W_hh + (size_t)lane * H_);
        const f32x4* pz = (const f32x4*)(W_hh + (size_t)(64 + lane) * H_);
        const f32x4* pn = (const f32x4*)(W_hh + (size_t)(128 + lane) * H_);
        #pragma unroll
        for (int q = 0; q < 16; ++q) {
            f32x4 vr = pr[q], vz = pz[q], vn = pn[q];
            wr[2*q] = f32x2{vr.x, vr.y}; wr[2*q+1] = f32x2{vr.z, vr.w};
            wz[2*q] = f32x2{vz.x, vz.y}; wz[2*q+1] = f32x2{vz.z, vz.w};
            wn[2*q] = f32x2{vn.x, vn.y}; wn[2*q+1] = f32x2{vn.z, vn.w};
        }
    }
    // ---- launder: make weight defs opaque -> forced loop-carried VGPR
    //      residency (loads can't be sunk/remat'd into the time loop) ----
    #pragma unroll
    for (int i = 0; i < 32; ++i) {
        asm volatile("" : "+v"(wr[i]), "+v"(wz[i]), "+v"(wn[i]));
    }

    const float wihr = W_ih[lane];
    const float wihz = W_ih[64 + lane];
    const float wihn = W_ih[128 + lane];
    const float br   = b_ih[lane]      + b_hh[lane];
    const float bz   = b_ih[64 + lane] + b_hh[64 + lane];
    const float bhn  = b_hh[128 + lane];
    const float bin  = b_ih[128 + lane];

    const float* __restrict__ xrow = x + (size_t)b * T_;
    float* __restrict__ orow = out + (size_t)b * T_;

    shh[lane] = 0.0f;          // h0 = 0 (single wave: LDS pipe is in-order)

    float h_own = 0.0f;
    float xa = xrow[lane];     // current 64-step block of x
    float xb = 0.0f;

    for (int tb = 0; tb < T_ / 64; ++tb) {
        if (tb < T_ / 64 - 1) xb = xrow[(tb + 1) * 64 + lane];  // prefetch
        float oval = 0.0f;

        #pragma unroll 8
        for (int t2 = 0; t2 < 64; ++t2) {
            const float xt  = readlane_f(xa, t2);
            const float xpr = fmaf(xt, wihr, br);
            const float xpz = fmaf(xt, wihz, bz);
            const float xpn = fmaf(xt, wihn, bin);

            // h: 16 broadcast ds_read_b128 (uniform addr, conflict-free)
            f32x4 hv[16];
            const f32x4* hp = (const f32x4*)shh;
            #pragma unroll
            for (int q = 0; q < 16; ++q) hv[q] = hp[q];

            // 4 accumulators per gate: dep chain 8 deep instead of 16
            f32x2 ar[4], az[4], an[4];
            #pragma unroll
            for (int i = 0; i < 4; ++i) {
                ar[i] = f32x2{0.f, 0.f};
                az[i] = f32x2{0.f, 0.f};
                an[i] = f32x2{0.f, 0.f};
            }
            #pragma unroll
            for (int q = 0; q < 16; ++q) {
                f32x2 h0 = {hv[q].x, hv[q].y};
                f32x2 h1 = {hv[q].z, hv[q].w};
                const int a0 = (q & 1) * 2, a1 = a0 + 1;
                pk_fma(ar[a0], wr[2*q], h0);  pk_fma(ar[a1], wr[2*q+1], h1);
                pk_fma(az[a0], wz[2*q], h0);  pk_fma(az[a1], wz[2*q+1], h1);
                pk_fma(an[a0], wn[2*q], h0);  pk_fma(an[a1], wn[2*q+1], h1);
            }
            f32x2 sr2 = pk_add(pk_add(ar[0], ar[2]), pk_add(ar[1], ar[3]));
            f32x2 sz2 = pk_add(pk_add(az[0], az[2]), pk_add(az[1], az[3]));
            f32x2 sn2 = pk_add(pk_add(an[0], an[2]), pk_add(an[1], an[3]));

            float r  = fast_sigmoid(sr2.x + sr2.y + xpr);
            float z  = fast_sigmoid(sz2.x + sz2.y + xpz);
            float hn = sn2.x + sn2.y + bhn;
            float n  = fast_tanh(fmaf(r, hn, xpn));
            float h_new = n + z * (h_own - n);   // (1-z)*n + z*h
            h_own = h_new;

            shh[lane] = h_new;                   // publish for next step

            float h63 = readlane_f(h_new, 63);
            oval = (t2 == lane) ? h63 : oval;    // latch out[t]
        }

        orow[tb * 64 + lane] = oval;             // coalesced 256B store
        xa = xb;
    }
}

extern "C" void kernel_launch(void* const* d_in, const int* in_sizes, int n_in,
                              void* d_out, int out_size, void* d_ws, size_t ws_size,
                              hipStream_t stream) {
    const float* x    = (const float*)d_in[0];
    const float* W_ih = (const float*)d_in[1];
    const float* W_hh = (const float*)d_in[2];
    const float* b_ih = (const float*)d_in[3];
    const float* b_hh = (const float*)d_in[4];
    float* out = (float*)d_out;

    dim3 grid(B_), block(64);
    gru_kernel<<<grid, block, 0, stream>>>(x, W_ih, W_hh, b_ih, b_hh, out);
}

// Round 5
// 813.887 us; speedup vs baseline: 1.1753x; 1.1753x over previous
//
#include <hip/hip_runtime.h>

#define B_ 256
#define T_ 2048
#define H_ 64

typedef float f32x2 __attribute__((ext_vector_type(2)));
typedef float f32x4 __attribute__((ext_vector_type(4)));

__device__ __forceinline__ void pk_fma(f32x2& d, f32x2 a, f32x2 b) {
    asm("v_pk_fma_f32 %0, %1, %2, %0" : "+v"(d) : "v"(a), "v"(b));
}
__device__ __forceinline__ f32x2 pk_add(f32x2 a, f32x2 b) {
    f32x2 d;
    asm("v_pk_add_f32 %0, %1, %2" : "=v"(d) : "v"(a), "v"(b));
    return d;
}

__device__ __forceinline__ float fast_sigmoid(float v) {
    float e = __builtin_amdgcn_exp2f(-1.4426950408889634f * v);
    return __builtin_amdgcn_rcpf(1.0f + e);
}
__device__ __forceinline__ float fast_tanh(float v) {
    float e = __builtin_amdgcn_exp2f(2.8853900817779268f * v);
    return fmaf(-2.0f, __builtin_amdgcn_rcpf(1.0f + e), 1.0f);
}
__device__ __forceinline__ float readlane_f(float v, int idx) {
    return __builtin_bit_cast(float,
        __builtin_amdgcn_readlane(__builtin_bit_cast(int, v), idx));
}

// 4 waves per batch row, K-SPLIT: wave w owns k in [16w,16w+16). Lane j keeps
// rows {j,64+j,128+j} x 16 cols = 48 weight VGPRs (total pressure ~100 --
// comfortably under the 256 architectural cap, unlike R2-R4's infeasible 310).
// Per step: 24 pk_fma -> 3 LDS partial writes -> 1 barrier -> redundant
// 4-way reduce + activations in every wave -> h slice rebuilt intra-wave via
// 16 v_readlane (h_new[j] lives in lane j of EVERY wave; no 2nd barrier).
// part[] is double-buffered: reads of buf pb complete before barrier(t+1),
// writes to pb resume only after it.
__global__ __launch_bounds__(256, 1)
void gru_kernel(const float* __restrict__ x,
                const float* __restrict__ W_ih,
                const float* __restrict__ W_hh,
                const float* __restrict__ b_ih,
                const float* __restrict__ b_hh,
                float* __restrict__ out)
{
    __shared__ float part[2][3][4][64];   // [buf][gate][wave][lane]

    const int tid  = threadIdx.x;
    const int lane = tid & 63;
    const int w    = tid >> 6;            // k-slice owner
    const int k0   = w * 16;
    const int b    = blockIdx.x;

    // ---- preload W_hh rows {lane,64+lane,128+lane}, cols [k0,k0+16) ----
    f32x2 wr[8], wz[8], wn[8];
    {
        const f32x4* pr = (const f32x4*)(W_hh + (size_t)lane * H_ + k0);
        const f32x4* pz = (const f32x4*)(W_hh + (size_t)(64 + lane) * H_ + k0);
        const f32x4* pn = (const f32x4*)(W_hh + (size_t)(128 + lane) * H_ + k0);
        #pragma unroll
        for (int q = 0; q < 4; ++q) {
            f32x4 vr = pr[q], vz = pz[q], vn = pn[q];
            wr[2*q] = f32x2{vr.x, vr.y}; wr[2*q+1] = f32x2{vr.z, vr.w};
            wz[2*q] = f32x2{vz.x, vz.y}; wz[2*q+1] = f32x2{vz.z, vz.w};
            wn[2*q] = f32x2{vn.x, vn.y}; wn[2*q+1] = f32x2{vn.z, vn.w};
        }
    }
    #pragma unroll
    for (int i = 0; i < 8; ++i)
        asm volatile("" : "+v"(wr[i]), "+v"(wz[i]), "+v"(wn[i]));

    // per-channel params (channel = lane; identical in all waves)
    const float wihr = W_ih[lane];
    const float wihz = W_ih[64 + lane];
    const float wihn = W_ih[128 + lane];
    const float br   = b_ih[lane]      + b_hh[lane];
    const float bz   = b_ih[64 + lane] + b_hh[64 + lane];
    const float bhn  = b_hh[128 + lane];
    const float bin  = b_ih[128 + lane];

    const float* __restrict__ xrow = x + (size_t)b * T_;
    float* __restrict__ orow = out + (size_t)b * T_;

    // h slice [k0,k0+16) replicated across this wave's lanes; h_own = h[lane]
    f32x2 hs[8];
    #pragma unroll
    for (int i = 0; i < 8; ++i) hs[i] = f32x2{0.f, 0.f};
    float h_own = 0.0f;
    float oval  = 0.0f;
    float xa = xrow[lane];                 // current 64-step block of x
    float xb = 0.0f;

    for (int tb = 0; tb < T_ / 64; ++tb) {
        if (tb < T_ / 64 - 1) xb = xrow[(tb + 1) * 64 + lane];

        #pragma unroll 8
        for (int t2 = 0; t2 < 64; ++t2) {
            const int pb = t2 & 1;
            const float xt  = readlane_f(xa, t2);
            const float xpr = fmaf(xt, wihr, br);
            const float xpz = fmaf(xt, wihz, bz);
            const float xpn = fmaf(xt, wihn, bin);

            // ---- partial dots over my 16 k's (2 chains/gate, 4 deep) ----
            f32x2 ar0 = {0.f,0.f}, ar1 = {0.f,0.f};
            f32x2 az0 = {0.f,0.f}, az1 = {0.f,0.f};
            f32x2 an0 = {0.f,0.f}, an1 = {0.f,0.f};
            #pragma unroll
            for (int q = 0; q < 8; q += 2) {
                pk_fma(ar0, wr[q], hs[q]);  pk_fma(ar1, wr[q+1], hs[q+1]);
                pk_fma(az0, wz[q], hs[q]);  pk_fma(az1, wz[q+1], hs[q+1]);
                pk_fma(an0, wn[q], hs[q]);  pk_fma(an1, wn[q+1], hs[q+1]);
            }
            f32x2 sr2 = pk_add(ar0, ar1);
            f32x2 sz2 = pk_add(az0, az1);
            f32x2 sn2 = pk_add(an0, an1);

            part[pb][0][w][lane] = sr2.x + sr2.y;
            part[pb][1][w][lane] = sz2.x + sz2.y;
            part[pb][2][w][lane] = sn2.x + sn2.y;
            __syncthreads();

            // ---- redundant reduce + activations (identical in all waves) ----
            float sr = (part[pb][0][0][lane] + part[pb][0][1][lane])
                     + (part[pb][0][2][lane] + part[pb][0][3][lane]);
            float sz = (part[pb][1][0][lane] + part[pb][1][1][lane])
                     + (part[pb][1][2][lane] + part[pb][1][3][lane]);
            float sn = (part[pb][2][0][lane] + part[pb][2][1][lane])
                     + (part[pb][2][2][lane] + part[pb][2][3][lane]);

            float r  = fast_sigmoid(sr + xpr);
            float z  = fast_sigmoid(sz + xpz);
            float n  = fast_tanh(fmaf(r, sn + bhn, xpn));
            float h_new = n + z * (h_own - n);   // (1-z)*n + z*h
            h_own = h_new;

            // ---- rebuild my k-slice from my own wave's lanes ----
            #pragma unroll
            for (int i = 0; i < 8; ++i) {
                float e0 = readlane_f(h_new, k0 + 2*i);
                float e1 = readlane_f(h_new, k0 + 2*i + 1);
                hs[i] = f32x2{e0, e1};
            }

            float h63 = readlane_f(h_new, 63);
            oval = (t2 == lane) ? h63 : oval;    // latch out[t]
        }

        if (w == 0) orow[tb * 64 + lane] = oval; // coalesced 256B store
        xa = xb;
    }
}

extern "C" void kernel_launch(void* const* d_in, const int* in_sizes, int n_in,
                              void* d_out, int out_size, void* d_ws, size_t ws_size,
                              hipStream_t stream) {
    const float* x    = (const float*)d_in[0];
    const float* W_ih = (const float*)d_in[1];
    const float* W_hh = (const float*)d_in[2];
    const float* b_ih = (const float*)d_in[3];
    const float* b_hh = (const float*)d_in[4];
    float* out = (float*)d_out;

    dim3 grid(B_), block(256);
    gru_kernel<<<grid, block, 0, stream>>>(x, W_ih, W_hh, b_ih, b_hh, out);
}

// Round 6
// 749.571 us; speedup vs baseline: 1.2762x; 1.0858x over previous
//
#include <hip/hip_runtime.h>

#define B_ 256
#define T_ 2048
#define H_ 64

typedef float f32x4 __attribute__((ext_vector_type(4)));

__device__ __forceinline__ float fast_sigmoid(float v) {
    float e = __builtin_amdgcn_exp2f(-1.4426950408889634f * v);
    return __builtin_amdgcn_rcpf(1.0f + e);
}
__device__ __forceinline__ float fast_tanh(float v) {
    float e = __builtin_amdgcn_exp2f(2.8853900817779268f * v);
    return fmaf(-2.0f, __builtin_amdgcn_rcpf(1.0f + e), 1.0f);
}
__device__ __forceinline__ float readlane_f(float v, int idx) {
    return __builtin_bit_cast(float,
        __builtin_amdgcn_readlane(__builtin_bit_cast(int, v), idx));
}

// 4 waves per batch row, K-split: wave w owns k in [16w,16w+16). Lane j keeps
// rows {j,64+j,128+j} x its wave's 16 cols = 48 weight floats. NO inline asm
// this round: R5's asm "v"-constraints forced v_accvgpr_read copies around
// every pk_fma (~150 extra instrs/step, VALUBusy 51%). Plain fmaf lets the
// compiler source AGPR/VGPR weights directly. h k-slice is held as
// wave-UNIFORM scalars (readlane results -> SGPRs), consumed as the SGPR
// operand of v_fmac -- no VGPR copies, and the rebuild is 16 readlanes flat.
// Per step: 48 fma -> 3 ds_write_b32 -> 1 barrier -> 12 ds_read_b32 + 9 adds
// -> activations -> h_new -> 16 readlane rebuild. One barrier, zero conflicts.
__global__ __launch_bounds__(256, 1)
void gru_kernel(const float* __restrict__ x,
                const float* __restrict__ W_ih,
                const float* __restrict__ W_hh,
                const float* __restrict__ b_ih,
                const float* __restrict__ b_hh,
                float* __restrict__ out)
{
    __shared__ float part[2][3][4][64];   // [buf][gate][wave][channel]

    const int tid  = threadIdx.x;
    const int lane = tid & 63;
    const int w    = tid >> 6;
    const int k0   = w * 16;
    const int b    = blockIdx.x;

    // ---- preload W_hh rows {lane,64+lane,128+lane}, cols [k0,k0+16) ----
    float wr[16], wz[16], wn[16];
    {
        const f32x4* pr = (const f32x4*)(W_hh + (size_t)lane * H_ + k0);
        const f32x4* pz = (const f32x4*)(W_hh + (size_t)(64 + lane) * H_ + k0);
        const f32x4* pn = (const f32x4*)(W_hh + (size_t)(128 + lane) * H_ + k0);
        #pragma unroll
        for (int q = 0; q < 4; ++q) {
            f32x4 vr = pr[q], vz = pz[q], vn = pn[q];
            wr[4*q] = vr.x; wr[4*q+1] = vr.y; wr[4*q+2] = vr.z; wr[4*q+3] = vr.w;
            wz[4*q] = vz.x; wz[4*q+1] = vz.y; wz[4*q+2] = vz.z; wz[4*q+3] = vz.w;
            wn[4*q] = vn.x; wn[4*q+1] = vn.y; wn[4*q+2] = vn.z; wn[4*q+3] = vn.w;
        }
    }

    // per-channel params (channel = lane; identical across waves)
    const float wihr = W_ih[lane];
    const float wihz = W_ih[64 + lane];
    const float wihn = W_ih[128 + lane];
    const float br   = b_ih[lane]      + b_hh[lane];
    const float bz   = b_ih[64 + lane] + b_hh[64 + lane];
    const float bhn  = b_hh[128 + lane];
    const float bin  = b_ih[128 + lane];

    const float* __restrict__ xrow = x + (size_t)b * T_;
    float* __restrict__ orow = out + (size_t)b * T_;

    // h slice [k0,k0+16): wave-uniform scalars (SGPR-resident)
    float hs[16];
    #pragma unroll
    for (int i = 0; i < 16; ++i) hs[i] = 0.0f;
    float h_own = 0.0f;
    float oval  = 0.0f;
    float xa = xrow[lane];
    float xb = 0.0f;

    for (int tb = 0; tb < T_ / 64; ++tb) {
        if (tb < T_ / 64 - 1) xb = xrow[(tb + 1) * 64 + lane];

        #pragma unroll 4
        for (int t2 = 0; t2 < 64; ++t2) {
            const int pb = t2 & 1;
            const float xt  = readlane_f(xa, t2);     // uniform -> SGPR
            const float xpr = fmaf(xt, wihr, br);
            const float xpz = fmaf(xt, wihz, bz);
            const float xpn = fmaf(xt, wihn, bin);

            // ---- partial dots over my 16 k's: v_fmac v, s(hs), v(w) ----
            float ar0 = 0.f, ar1 = 0.f, az0 = 0.f, az1 = 0.f,
                  an0 = 0.f, an1 = 0.f;
            #pragma unroll
            for (int q = 0; q < 16; q += 2) {
                ar0 = fmaf(wr[q], hs[q], ar0);  ar1 = fmaf(wr[q+1], hs[q+1], ar1);
                az0 = fmaf(wz[q], hs[q], az0);  az1 = fmaf(wz[q+1], hs[q+1], az1);
                an0 = fmaf(wn[q], hs[q], an0);  an1 = fmaf(wn[q+1], hs[q+1], an1);
            }
            // write each partial as soon as it's done (overlaps LDS latency)
            part[pb][0][w][lane] = ar0 + ar1;
            part[pb][1][w][lane] = az0 + az1;
            part[pb][2][w][lane] = an0 + an1;
            __syncthreads();

            // ---- redundant reduce + activations (all waves identical) ----
            float sr = (part[pb][0][0][lane] + part[pb][0][1][lane])
                     + (part[pb][0][2][lane] + part[pb][0][3][lane]);
            float sz = (part[pb][1][0][lane] + part[pb][1][1][lane])
                     + (part[pb][1][2][lane] + part[pb][1][3][lane]);
            float sn = (part[pb][2][0][lane] + part[pb][2][1][lane])
                     + (part[pb][2][2][lane] + part[pb][2][3][lane]);

            float r  = fast_sigmoid(sr + xpr);
            float z  = fast_sigmoid(sz + xpz);
            float n  = fast_tanh(fmaf(r, sn + bhn, xpn));
            float h_new = n + z * (h_own - n);   // (1-z)*n + z*h
            h_own = h_new;

            // ---- rebuild my k-slice: 16 readlanes -> SGPRs ----
            #pragma unroll
            for (int i = 0; i < 16; ++i) hs[i] = readlane_f(h_new, k0 + i);

            float h63 = readlane_f(h_new, 63);
            oval = (t2 == lane) ? h63 : oval;    // latch out[t]
        }

        if (w == 0) orow[tb * 64 + lane] = oval; // coalesced 256B store
        xa = xb;
    }
}

extern "C" void kernel_launch(void* const* d_in, const int* in_sizes, int n_in,
                              void* d_out, int out_size, void* d_ws, size_t ws_size,
                              hipStream_t stream) {
    const float* x    = (const float*)d_in[0];
    const float* W_ih = (const float*)d_in[1];
    const float* W_hh = (const float*)d_in[2];
    const float* b_ih = (const float*)d_in[3];
    const float* b_hh = (const float*)d_in[4];
    float* out = (float*)d_out;

    dim3 grid(B_), block(256);
    gru_kernel<<<grid, block, 0, stream>>>(x, W_ih, W_hh, b_ih, b_hh, out);
}

// Round 7
// 642.798 us; speedup vs baseline: 1.4881x; 1.1661x over previous
//
#include <hip/hip_runtime.h>

#define B_ 256
#define T_ 2048
#define H_ 64

typedef float f32x4 __attribute__((ext_vector_type(4)));
typedef _Float16 h16x2 __attribute__((ext_vector_type(2)));

__device__ __forceinline__ float fdot2(h16x2 a, h16x2 b, float c) {
#if __has_builtin(__builtin_amdgcn_fdot2)
    return __builtin_amdgcn_fdot2(a, b, c, false);   // v_dot2_f32_f16
#else
    float d;
    asm("v_dot2_f32_f16 %0, %1, %2, %3" : "=v"(d) : "v"(a), "v"(b), "v"(c));
    return d;
#endif
}

__device__ __forceinline__ float fast_sigmoid(float v) {
    float e = __builtin_amdgcn_exp2f(-1.4426950408889634f * v);
    return __builtin_amdgcn_rcpf(1.0f + e);
}
__device__ __forceinline__ float fast_tanh(float v) {
    float e = __builtin_amdgcn_exp2f(2.8853900817779268f * v);
    return fmaf(-2.0f, __builtin_amdgcn_rcpf(1.0f + e), 1.0f);
}
__device__ __forceinline__ float readlane_f(float v, int idx) {
    return __builtin_bit_cast(float,
        __builtin_amdgcn_readlane(__builtin_bit_cast(int, v), idx));
}

// SINGLE WAVE per batch row -- zero barriers. f16 weights packed as half2:
// all 3 gate rows for lane j's channel = 96 VGPRs -> genuinely feasible
// residency (~160 total pressure), unlike the fp32 variants (310+). Dots via
// v_dot2_f32_f16 (2 MAC/instr, fp32 accumulate): 96 instrs/step instead of
// 192 fp32 FMAs. h state: h_own stays fp32 in lane j (no accumulating
// quantization); dot-input h is f16 via a 128-byte LDS buffer -- 1
// ds_write_b16 + 8 broadcast ds_read_b128 per step, conflict-free, ordered
// by the wave's own lgkmcnt (no barrier needed).
__global__ __launch_bounds__(64, 1)
void gru_kernel(const float* __restrict__ x,
                const float* __restrict__ W_ih,
                const float* __restrict__ W_hh,
                const float* __restrict__ b_ih,
                const float* __restrict__ b_hh,
                float* __restrict__ out)
{
    __shared__ __align__(16) _Float16 shh[H_];

    const int lane = threadIdx.x;
    const int b    = blockIdx.x;

    // ---- preload W_hh rows {lane, 64+lane, 128+lane}, cvt to half2 ----
    h16x2 wr[32], wz[32], wn[32];
    {
        const f32x4* pr = (const f32x4*)(W_hh + (size_t)lane * H_);
        const f32x4* pz = (const f32x4*)(W_hh + (size_t)(64 + lane) * H_);
        const f32x4* pn = (const f32x4*)(W_hh + (size_t)(128 + lane) * H_);
        #pragma unroll
        for (int q = 0; q < 16; ++q) {
            f32x4 vr = pr[q], vz = pz[q], vn = pn[q];
            wr[2*q]   = h16x2{(_Float16)vr.x, (_Float16)vr.y};
            wr[2*q+1] = h16x2{(_Float16)vr.z, (_Float16)vr.w};
            wz[2*q]   = h16x2{(_Float16)vz.x, (_Float16)vz.y};
            wz[2*q+1] = h16x2{(_Float16)vz.z, (_Float16)vz.w};
            wn[2*q]   = h16x2{(_Float16)vn.x, (_Float16)vn.y};
            wn[2*q+1] = h16x2{(_Float16)vn.z, (_Float16)vn.w};
        }
    }
    // block remat/sinking of the load+cvt chains: one-time, zero-cost launder
    #pragma unroll
    for (int i = 0; i < 32; ++i)
        asm volatile("" : "+v"(wr[i]), "+v"(wz[i]), "+v"(wn[i]));

    const float wihr = W_ih[lane];
    const float wihz = W_ih[64 + lane];
    const float wihn = W_ih[128 + lane];
    const float br   = b_ih[lane]      + b_hh[lane];
    const float bz   = b_ih[64 + lane] + b_hh[64 + lane];
    const float bhn  = b_hh[128 + lane];
    const float bin  = b_ih[128 + lane];

    const float* __restrict__ xrow = x + (size_t)b * T_;
    float* __restrict__ orow = out + (size_t)b * T_;

    shh[lane] = (_Float16)0.0f;      // h0 = 0

    float h_own = 0.0f;
    float oval  = 0.0f;
    float xa = xrow[lane];           // current 64-step block of x
    float xb = 0.0f;

    for (int tb = 0; tb < T_ / 64; ++tb) {
        if (tb < T_ / 64 - 1) xb = xrow[(tb + 1) * 64 + lane];

        #pragma unroll 4
        for (int t2 = 0; t2 < 64; ++t2) {
            const float xt  = readlane_f(xa, t2);
            const float xpr = fmaf(xt, wihr, br);
            const float xpz = fmaf(xt, wihz, bz);
            const float xpn = fmaf(xt, wihn, bin);

            // ---- rebuild h: 8 broadcast ds_read_b128 (64 f16 = 128 B) ----
            h16x2 hh[32];
            const f32x4* hp = (const f32x4*)shh;
            #pragma unroll
            for (int q = 0; q < 8; ++q) {
                union { f32x4 f; h16x2 h[4]; } u;
                u.f = hp[q];
                hh[4*q]   = u.h[0];
                hh[4*q+1] = u.h[1];
                hh[4*q+2] = u.h[2];
                hh[4*q+3] = u.h[3];
            }

            // ---- 3 gate dots: 96 v_dot2_f32_f16, 4 chains/gate (8 deep) ----
            float ar[4] = {0,0,0,0}, az[4] = {0,0,0,0}, an[4] = {0,0,0,0};
            #pragma unroll
            for (int i = 0; i < 32; ++i) {
                const int a = i >> 3;
                ar[a] = fdot2(wr[i], hh[i], ar[a]);
                az[a] = fdot2(wz[i], hh[i], az[a]);
                an[a] = fdot2(wn[i], hh[i], an[a]);
            }
            float sr = (ar[0] + ar[1]) + (ar[2] + ar[3]);
            float sz = (az[0] + az[1]) + (az[2] + az[3]);
            float sn = (an[0] + an[1]) + (an[2] + an[3]);

            float r  = fast_sigmoid(sr + xpr);
            float z  = fast_sigmoid(sz + xpz);
            float n  = fast_tanh(fmaf(r, sn + bhn, xpn));
            float h_new = n + z * (h_own - n);   // (1-z)*n + z*h
            h_own = h_new;

            shh[lane] = (_Float16)h_new;         // publish for next step

            float h63 = readlane_f(h_new, 63);
            oval = (t2 == lane) ? h63 : oval;    // latch out[t]
        }

        orow[tb * 64 + lane] = oval;             // coalesced 256B store
        xa = xb;
    }
}

extern "C" void kernel_launch(void* const* d_in, const int* in_sizes, int n_in,
                              void* d_out, int out_size, void* d_ws, size_t ws_size,
                              hipStream_t stream) {
    const float* x    = (const float*)d_in[0];
    const float* W_ih = (const float*)d_in[1];
    const float* W_hh = (const float*)d_in[2];
    const float* b_ih = (const float*)d_in[3];
    const float* b_hh = (const float*)d_in[4];
    float* out = (float*)d_out;

    dim3 grid(B_), block(64);
    gru_kernel<<<grid, block, 0, stream>>>(x, W_ih, W_hh, b_ih, b_hh, out);
}

// Round 8
// 640.393 us; speedup vs baseline: 1.4937x; 1.0038x over previous
//
#include <hip/hip_runtime.h>

#define B_ 256
#define T_ 2048
#define H_ 64

typedef float f32x4 __attribute__((ext_vector_type(4)));
typedef _Float16 h16x2 __attribute__((ext_vector_type(2)));

__device__ __forceinline__ float fdot2(h16x2 a, h16x2 b, float c) {
#if __has_builtin(__builtin_amdgcn_fdot2)
    return __builtin_amdgcn_fdot2(a, b, c, false);   // v_dot2_f32_f16
#else
    float d;
    asm("v_dot2_f32_f16 %0, %1, %2, %3" : "=v"(d) : "v"(a), "v"(b), "v"(c));
    return d;
#endif
}

__device__ __forceinline__ float fast_sigmoid(float v) {
    float e = __builtin_amdgcn_exp2f(-1.4426950408889634f * v);
    return __builtin_amdgcn_rcpf(1.0f + e);
}
__device__ __forceinline__ float fast_tanh(float v) {
    float e = __builtin_amdgcn_exp2f(2.8853900817779268f * v);
    return fmaf(-2.0f, __builtin_amdgcn_rcpf(1.0f + e), 1.0f);
}
__device__ __forceinline__ float readlane_f(float v, int idx) {
    return __builtin_bit_cast(float,
        __builtin_amdgcn_readlane(__builtin_bit_cast(int, v), idx));
}

// SINGLE WAVE per batch row, zero barriers, f16 weights + v_dot2_f32_f16
// (R7 structure). R8 FIX: amdgpu_waves_per_eu(1,1). launch_bounds' second
// arg is only a MINIMUM occupancy; without a pinned maximum the allocator
// capped arch VGPRs at 92 and parked the 96 weight registers in AGPRs,
// paying v_accvgpr_read copies at every dot2 use (~160 extra instrs/step,
// the whole R7 gap). There is exactly 1 wave per CU -- occupancy is
// irrelevant -- so pin waves/EU to [1,1] and let the 96 weight h16x2 +
// 32 hh + accumulators (~155 regs) live in arch VGPRs copy-free.
__global__ __launch_bounds__(64, 1) __attribute__((amdgpu_waves_per_eu(1, 1)))
void gru_kernel(const float* __restrict__ x,
                const float* __restrict__ W_ih,
                const float* __restrict__ W_hh,
                const float* __restrict__ b_ih,
                const float* __restrict__ b_hh,
                float* __restrict__ out)
{
    __shared__ __align__(16) _Float16 shh[H_];

    const int lane = threadIdx.x;
    const int b    = blockIdx.x;

    // ---- preload W_hh rows {lane, 64+lane, 128+lane}, cvt to half2 ----
    h16x2 wr[32], wz[32], wn[32];
    {
        const f32x4* pr = (const f32x4*)(W_hh + (size_t)lane * H_);
        const f32x4* pz = (const f32x4*)(W_hh + (size_t)(64 + lane) * H_);
        const f32x4* pn = (const f32x4*)(W_hh + (size_t)(128 + lane) * H_);
        #pragma unroll
        for (int q = 0; q < 16; ++q) {
            f32x4 vr = pr[q], vz = pz[q], vn = pn[q];
            wr[2*q]   = h16x2{(_Float16)vr.x, (_Float16)vr.y};
            wr[2*q+1] = h16x2{(_Float16)vr.z, (_Float16)vr.w};
            wz[2*q]   = h16x2{(_Float16)vz.x, (_Float16)vz.y};
            wz[2*q+1] = h16x2{(_Float16)vz.z, (_Float16)vz.w};
            wn[2*q]   = h16x2{(_Float16)vn.x, (_Float16)vn.y};
            wn[2*q+1] = h16x2{(_Float16)vn.z, (_Float16)vn.w};
        }
    }
    // one-time launder: blocks remat/sinking of the load+cvt chains
    #pragma unroll
    for (int i = 0; i < 32; ++i)
        asm volatile("" : "+v"(wr[i]), "+v"(wz[i]), "+v"(wn[i]));

    const float wihr = W_ih[lane];
    const float wihz = W_ih[64 + lane];
    const float wihn = W_ih[128 + lane];
    const float br   = b_ih[lane]      + b_hh[lane];
    const float bz   = b_ih[64 + lane] + b_hh[64 + lane];
    const float bhn  = b_hh[128 + lane];
    const float bin  = b_ih[128 + lane];

    const float* __restrict__ xrow = x + (size_t)b * T_;
    float* __restrict__ orow = out + (size_t)b * T_;

    shh[lane] = (_Float16)0.0f;      // h0 = 0

    float h_own = 0.0f;
    float oval  = 0.0f;
    float xa = xrow[lane];           // current 64-step block of x
    float xb = 0.0f;

    for (int tb = 0; tb < T_ / 64; ++tb) {
        if (tb < T_ / 64 - 1) xb = xrow[(tb + 1) * 64 + lane];

        #pragma unroll 8
        for (int t2 = 0; t2 < 64; ++t2) {
            const float xt  = readlane_f(xa, t2);
            const float xpr = fmaf(xt, wihr, br);
            const float xpz = fmaf(xt, wihz, bz);
            const float xpn = fmaf(xt, wihn, bin);

            // ---- rebuild h: 8 broadcast ds_read_b128 (64 f16 = 128 B) ----
            h16x2 hh[32];
            const f32x4* hp = (const f32x4*)shh;
            #pragma unroll
            for (int q = 0; q < 8; ++q) {
                union { f32x4 f; h16x2 h[4]; } u;
                u.f = hp[q];
                hh[4*q]   = u.h[0];
                hh[4*q+1] = u.h[1];
                hh[4*q+2] = u.h[2];
                hh[4*q+3] = u.h[3];
            }

            // ---- 3 gate dots: 96 v_dot2_f32_f16, 4 chains/gate (8 deep) ----
            float ar[4] = {0,0,0,0}, az[4] = {0,0,0,0}, an[4] = {0,0,0,0};
            #pragma unroll
            for (int i = 0; i < 32; ++i) {
                const int a = i >> 3;
                ar[a] = fdot2(wr[i], hh[i], ar[a]);
                az[a] = fdot2(wz[i], hh[i], az[a]);
                an[a] = fdot2(wn[i], hh[i], an[a]);
            }
            float sr = (ar[0] + ar[1]) + (ar[2] + ar[3]);
            float sz = (az[0] + az[1]) + (az[2] + az[3]);
            float sn = (an[0] + an[1]) + (an[2] + an[3]);

            float r  = fast_sigmoid(sr + xpr);
            float z  = fast_sigmoid(sz + xpz);
            float n  = fast_tanh(fmaf(r, sn + bhn, xpn));
            float h_new = n + z * (h_own - n);   // (1-z)*n + z*h
            h_own = h_new;

            shh[lane] = (_Float16)h_new;         // publish for next step

            float h63 = readlane_f(h_new, 63);
            oval = (t2 == lane) ? h63 : oval;    // latch out[t]
        }

        orow[tb * 64 + lane] = oval;             // coalesced 256B store
        xa = xb;
    }
}

extern "C" void kernel_launch(void* const* d_in, const int* in_sizes, int n_in,
                              void* d_out, int out_size, void* d_ws, size_t ws_size,
                              hipStream_t stream) {
    const float* x    = (const float*)d_in[0];
    const float* W_ih = (const float*)d_in[1];
    const float* W_hh = (const float*)d_in[2];
    const float* b_ih = (const float*)d_in[3];
    const float* b_hh = (const float*)d_in[4];
    float* out = (float*)d_out;

    dim3 grid(B_), block(64);
    gru_kernel<<<grid, block, 0, stream>>>(x, W_ih, W_hh, b_ih, b_hh, out);
}